// Round 1
// baseline (629.357 us; speedup 1.0000x reference)
//
#include <hip/hip_runtime.h>

// DeformableFusionAcrossFocus — fp32 baseline
// x: (2,64,16,96,96) f32 | w_off: (6,64,3) | b_off: (6,) | w_def: (64,64,3) | b_def: (64,)
// out: (2,64,16,96,96) f32
//
// Block = one (b, h, w-tile of 4). pos = n*4 + w_local in [0,64).
// LDS: xs[c][n][w] 16KB, wd[o][ck] stride-196-padded 50KB, val[ck][pos] 48KB, params ~11KB.

#define SMEM_FLOATS (4096 + 12544 + 12288 + 1152 + 384 + 192 + 192 + 192 + 192 + 8 + 64)
#define SMEM_BYTES (SMEM_FLOATS * 4)

__global__ __launch_bounds__(256) void deform_kernel(
    const float* __restrict__ x, const float* __restrict__ w_off,
    const float* __restrict__ b_off, const float* __restrict__ w_def,
    const float* __restrict__ b_def, float* __restrict__ out)
{
  extern __shared__ float smem[];
  float* xs   = smem;                 // [c*64 + n*4 + w]  4096
  float* wd   = xs + 4096;            // [o*196 + ck]      12544 (pad 192->196)
  float* val  = wd + 12544;           // [ck*64 + pos]     12288
  float* woff = val + 12288;          // [o*192 + c*3 + k] 1152
  float* offs = woff + 1152;          // [o*64 + pos]      384
  int*   p0   = (int*)(offs + 384);   // [k*64 + pos]      192
  int*   p1   = p0 + 192;             // 192
  float* wt0  = (float*)(p1 + 192);   // 192
  float* wt1  = wt0 + 192;            // 192
  float* bo   = wt1 + 192;            // 8
  float* bd   = bo + 8;               // 64

  const int t   = threadIdx.x;
  const int blk = blockIdx.x;
  const int wt_ = blk % 24;
  const int h   = (blk / 24) % 96;
  const int b   = blk / (24 * 96);
  const int base_hw = h * 96 + wt_ * 4;

  // ---- A0: stage x tile, w_def (transposed-padded), w_off, biases ----
  for (int i4 = t; i4 < 1024; i4 += 256) {
    int c = i4 >> 4, n = i4 & 15;
    const float4 v = *(const float4*)(x + (size_t)((b * 64 + c) * 16 + n) * 9216 + base_hw);
    *(float4*)(xs + c * 64 + n * 4) = v;
  }
  for (int i = t; i < 12288; i += 256) {
    int o = i / 192, ck = i - o * 192;
    wd[o * 196 + ck] = w_def[i];
  }
  for (int i = t; i < 1152; i += 256) woff[i] = w_off[i];
  if (t < 6)  bo[t] = b_off[t];
  if (t < 64) bd[t] = b_def[t];
  __syncthreads();

  // ---- A1: offsets conv1d (K=3, pad 1) ----
  for (int item = t; item < 384; item += 256) {
    int o = item >> 6, pos = item & 63;
    int w = pos & 3, n = pos >> 2;
    float acc = bo[o];
    const float* wo = woff + o * 192;
    const bool vm = (n >= 1), vp = (n <= 14);
    #pragma unroll 8
    for (int c = 0; c < 64; ++c) {
      float xm1 = vm ? xs[c * 64 + (n - 1) * 4 + w] : 0.f;
      float x00 = xs[c * 64 + n * 4 + w];
      float xp1 = vp ? xs[c * 64 + (n + 1) * 4 + w] : 0.f;
      acc = fmaf(xm1, wo[c * 3 + 0], acc);
      acc = fmaf(x00, wo[c * 3 + 1], acc);
      acc = fmaf(xp1, wo[c * 3 + 2], acc);
    }
    offs[o * 64 + pos] = acc;
  }
  __syncthreads();

  // ---- A1b: interpolation params per (k, pos) ----
  if (t < 192) {
    int k = t >> 6, pos = t & 63;
    int n = pos >> 2;
    float oy = offs[(2 * k) * 64 + pos];
    float ox = offs[(2 * k + 1) * 64 + pos];
    float px = (float)(n - 1 + k) + ox;
    float x0f = floorf(px);
    float fx = px - x0f;
    int x0 = (int)x0f;
    int x1 = x0 + 1;
    float wy = fmaxf(0.f, 1.f - fabsf(oy));
    float w0v = (x0 >= 0 && x0 < 16) ? (1.f - fx) * wy : 0.f;
    float w1v = (x1 >= 0 && x1 < 16) ? fx * wy : 0.f;
    p0[t] = min(max(x0, 0), 15);
    p1[t] = min(max(x1, 0), 15);
    wt0[t] = w0v;
    wt1[t] = w1v;
  }
  __syncthreads();

  // ---- A2: val[ck][pos] = bilinear gather * weights ----
  for (int i = t; i < 12288; i += 256) {
    int ck = i >> 6, pos = i & 63;
    int c = ck / 3, k = ck - c * 3;
    int kp = k * 64 + pos;
    int wl = pos & 3;
    float v0 = xs[c * 64 + p0[kp] * 4 + wl];
    float v1 = xs[c * 64 + p1[kp] * 4 + wl];
    val[ck * 64 + pos] = v0 * wt0[kp] + v1 * wt1[kp];
  }
  __syncthreads();

  // ---- B: out[o][pos] = sum_ck wd[o][ck] * val[ck][pos], 4x4 register tile ----
  const int og = t >> 4, pg = t & 15;
  const int o0 = og * 4, pos0 = pg * 4;
  float acc[4][4];
  #pragma unroll
  for (int i = 0; i < 4; ++i) {
    float bv = bd[o0 + i];
    #pragma unroll
    for (int p = 0; p < 4; ++p) acc[i][p] = bv;
  }

  for (int ckb = 0; ckb < 192; ckb += 4) {
    float4 vv[4], wv[4];
    #pragma unroll
    for (int j = 0; j < 4; ++j) vv[j] = *(float4*)(val + (ckb + j) * 64 + pos0);
    #pragma unroll
    for (int i = 0; i < 4; ++i) wv[i] = *(float4*)(wd + (o0 + i) * 196 + ckb);
    #pragma unroll
    for (int i = 0; i < 4; ++i) {
      const float* wi = (const float*)&wv[i];
      #pragma unroll
      for (int j = 0; j < 4; ++j) {
        float wij = wi[j];
        acc[i][0] = fmaf(wij, vv[j].x, acc[i][0]);
        acc[i][1] = fmaf(wij, vv[j].y, acc[i][1]);
        acc[i][2] = fmaf(wij, vv[j].z, acc[i][2]);
        acc[i][3] = fmaf(wij, vv[j].w, acc[i][3]);
      }
    }
  }

  // ---- epilogue: pos0..pos0+3 share n = pg, w = 0..3 -> float4 store ----
  const int n = pg;
  #pragma unroll
  for (int i = 0; i < 4; ++i) {
    int o = o0 + i;
    float4 r = make_float4(acc[i][0], acc[i][1], acc[i][2], acc[i][3]);
    *(float4*)(out + (size_t)((b * 64 + o) * 16 + n) * 9216 + base_hw) = r;
  }
}

extern "C" void kernel_launch(void* const* d_in, const int* in_sizes, int n_in,
                              void* d_out, int out_size, void* d_ws, size_t ws_size,
                              hipStream_t stream) {
  (void)in_sizes; (void)n_in; (void)d_ws; (void)ws_size; (void)out_size;
  static bool attr_set = false;
  if (!attr_set) {
    (void)hipFuncSetAttribute((const void*)deform_kernel,
                              hipFuncAttributeMaxDynamicSharedMemorySize, SMEM_BYTES);
    attr_set = true;
  }
  const float* x     = (const float*)d_in[0];
  const float* w_off = (const float*)d_in[1];
  const float* b_off = (const float*)d_in[2];
  const float* w_def = (const float*)d_in[3];
  const float* b_def = (const float*)d_in[4];
  float* out = (float*)d_out;

  deform_kernel<<<dim3(2 * 96 * 24), dim3(256), SMEM_BYTES, stream>>>(
      x, w_off, b_off, w_def, b_def, out);
}

// Round 3
// 249.214 us; speedup vs baseline: 2.5254x; 2.5254x over previous
//
#include <hip/hip_runtime.h>
#include <stdint.h>

// DeformableFusionAcrossFocus — bf16 MFMA, fixed tap clamping + staged float4 epilogue
// x:(2,64,16,96,96) f32 | w_off:(6,64,3) | b_off:(6) | w_def:(64,64,3) | b_def:(64) -> out:(2,64,16,96,96) f32
// Tile = (b,h, 8-wide w strip): pos = n*8+w in [0,128). Grid 768 blocks x 3 tiles.
// GEMM k-dim permutation: kk -> (c = kk&63, k3 = kk>>6), shared by A-frags and B (val/xs) producers.

typedef __attribute__((ext_vector_type(8))) short short8;
typedef __attribute__((ext_vector_type(4))) float f32x4;

#define XS0_OFF    0        // 32768 B : xs buf0  [c][16][8] f32 (rows lane-contiguous for DMA)
#define XS1_OFF    32768    // 32768 B : xs buf1
#define VALT_OFF   65536    // 51200 B : val [pos][200] bf16 (row stride 400B, 192 cols used)
                            //           reused post-GEMM as f32 out staging [o][132]
#define WDEF_OFF   116736   // 24576 B : w_def frag-linear (4 mt x 6 ks x 64 lane x 16B)
#define WOFF_OFF   141312   //  6144 B : w_off frag-linear (6 ks x 64 lane x 16B)
#define OFFS_OFF   147456   //  3072 B : offsets [6][128] f32
#define AAB_OFF    150528   //  3072 B : tap weights (a0,a1) f32 per (k*128+pos)
#define R0O_OFF    153600   //  1536 B : tap base float-offset per (k*128+pos)
#define LDS_BYTES  155136

__device__ __forceinline__ short f2bf(float f) {
  union { float f; uint32_t u; } v; v.f = f;
  uint32_t r = (v.u + 0x7FFFu + ((v.u >> 16) & 1u)) >> 16;
  return (short)r;
}

__device__ __forceinline__ void gl_lds16(const float* g, float* l) {
  __builtin_amdgcn_global_load_lds(
      (const __attribute__((address_space(1))) uint32_t*)g,
      (__attribute__((address_space(3))) uint32_t*)l, 16, 0, 0);
}

__global__ __launch_bounds__(256) void deform_kernel(
    const float* __restrict__ x, const float* __restrict__ w_off,
    const float* __restrict__ b_off, const float* __restrict__ w_def,
    const float* __restrict__ b_def, float* __restrict__ out)
{
  extern __shared__ char smem[];
  float* xsbuf0 = (float*)(smem + XS0_OFF);
  float* xsbuf1 = (float*)(smem + XS1_OFF);
  float* offs = (float*)(smem + OFFS_OFF);
  float* aab  = (float*)(smem + AAB_OFF);
  int*   r0o  = (int*)(smem + R0O_OFF);
  float* stg  = (float*)(smem + VALT_OFF);   // epilogue staging, stride 132 f32

  const int t  = threadIdx.x;
  const int wv = t >> 6;        // wave id 0..3 (= output m-tile in phase B)
  const int l  = t & 63;        // lane
  const int col = l & 15;       // MFMA n/col index
  const int rg  = l >> 4;       // MFMA row group
  const int p = blockIdx.x;

  // ---- prefetch x tile 0 (DMA global->LDS, 32 x 1KB instrs) ----
  {
    int tn = p * 3;
    int wt = tn % 12, bh = tn / 12;
    int h = bh % 96, b = bh / 96, w0 = wt * 8;
    const float* xb = x + (size_t)b * 64 * 16 * 9216 + h * 96 + w0;
    for (int s = 0; s < 8; ++s) {
      int q = wv * 8 + s;
      int R = q * 32 + (l >> 1);       // row id = c*16+n, 32B (8 f32) per row
      gl_lds16(xb + (size_t)R * 9216 + (l & 1) * 4, xsbuf0 + q * 256);
    }
  }

  // ---- one-time: build w_def frags (frag-linear, k-permuted) ----
  for (int q = t; q < 1536; q += 256) {           // q = (mt*6+ks)*64 + lane
    int mt = q / 384, ks = (q % 384) >> 6, ll = q & 63;
    int m = mt * 16 + (ll & 15), rgq = ll >> 4;
    short8 v;
    #pragma unroll
    for (int jj = 0; jj < 8; ++jj) {
      int kk = ks * 32 + rgq * 8 + jj;
      int c = kk & 63, k3 = kk >> 6;
      v[jj] = f2bf(w_def[m * 192 + c * 3 + k3]);
    }
    *(short8*)(smem + WDEF_OFF + q * 16) = v;
  }
  // ---- one-time: w_off frags (rows 6..15 zero) ----
  for (int q = t; q < 384; q += 256) {            // q = ks*64 + lane
    int ks = q >> 6, ll = q & 63;
    int m = ll & 15, rgq = ll >> 4;
    short8 v;
    #pragma unroll
    for (int jj = 0; jj < 8; ++jj) {
      int kk = ks * 32 + rgq * 8 + jj;
      int c = kk & 63, k3 = kk >> 6;
      v[jj] = (m < 6) ? f2bf(w_off[m * 192 + c * 3 + k3]) : (short)0;
    }
    *(short8*)(smem + WOFF_OFF + q * 16) = v;
  }
  float bdv[4];
  #pragma unroll
  for (int r = 0; r < 4; ++r) bdv[r] = b_def[wv * 16 + rg * 4 + r];

  __syncthreads();  // also drains tile-0 DMA

  for (int j = 0; j < 3; ++j) {
    int tn = p * 3 + j;
    int wt = tn % 12, bh = tn / 12;
    int h = bh % 96, b = bh / 96, w0 = wt * 8;
    float* xc = (j & 1) ? xsbuf1 : xsbuf0;

    // ---- offsets conv via MFMA (B-frags built on the fly from fp32 xs) ----
    #pragma unroll
    for (int nt2 = 0; nt2 < 2; ++nt2) {
      int nt = wv * 2 + nt2;
      int pos = nt * 16 + col;
      int n = pos >> 3, w = pos & 7;
      f32x4 acc = {0.f, 0.f, 0.f, 0.f};
      for (int ks = 0; ks < 6; ++ks) {
        short8 bv;
        #pragma unroll
        for (int jj = 0; jj < 8; ++jj) {
          int kk = ks * 32 + rg * 8 + jj;
          int c = kk & 63, k3 = kk >> 6;
          int row = n + k3 - 1;
          float v = (row >= 0 && row < 16) ? xc[c * 128 + row * 8 + w] : 0.f;
          bv[jj] = f2bf(v);
        }
        short8 av = *(short8*)(smem + WOFF_OFF + (ks * 64 + l) * 16);
        acc = __builtin_amdgcn_mfma_f32_16x16x32_bf16(av, bv, acc, 0, 0, 0);
      }
      #pragma unroll
      for (int r = 0; r < 4; ++r) {
        int row = rg * 4 + r;
        if (row < 6) offs[row * 128 + pos] = acc[r];
      }
    }
    __syncthreads();

    // ---- interpolation params per (k, pos) ----
    // Taps at rows r0, r0+1, both guaranteed in [0,15]; clipping folded into a0/a1.
    for (int it = t; it < 384; it += 256) {
      int k = it >> 7, pos = it & 127;
      int n = pos >> 3, w = pos & 7;
      float oy = offs[(2 * k) * 128 + pos] + b_off[2 * k];
      float ox = offs[(2 * k + 1) * 128 + pos] + b_off[2 * k + 1];
      float px = (float)(n - 1 + k) + ox;
      float x0f = floorf(px);
      float fx = px - x0f;
      int x0 = (int)x0f;
      float wy = fmaxf(0.f, 1.f - fabsf(oy));
      float wt1 = fx * wy;
      float wt0 = wy - wt1;               // (1-fx)*wy
      float a0, a1; int r0;
      if (x0 >= 0 && x0 < 15)      { r0 = x0; a0 = wt0; a1 = wt1; }
      else if (x0 == 15)           { r0 = 14; a0 = 0.f; a1 = wt0; }  // only tap row 15 (=x0)
      else if (x0 == -1)           { r0 = 0;  a0 = wt1; a1 = 0.f; }  // only tap row 0  (=x1)
      else                         { r0 = 0;  a0 = 0.f; a1 = 0.f; }
      aab[it * 2] = a0; aab[it * 2 + 1] = a1;
      r0o[it] = r0 * 8 + w;               // float offset within channel
    }
    __syncthreads();

    // ---- val gather: val[pos][k3*64+c] bf16 (B-operand layout) ----
    for (int it = t; it < 384; it += 256) {
      int k = it >> 7, pos = it & 127;
      float a0 = aab[it * 2], a1 = aab[it * 2 + 1];
      const float* xp = xc + r0o[it];
      uint32_t* dst = (uint32_t*)(smem + VALT_OFF) + pos * 100 + k * 32;
      #pragma unroll 8
      for (int c = 0; c < 64; c += 2) {
        float v0 = xp[c * 128],       v1 = xp[c * 128 + 8];   // ds_read2 pair
        float u0 = xp[c * 128 + 128], u1 = xp[c * 128 + 136];
        float q0 = v0 * a0 + v1 * a1;
        float q1 = u0 * a0 + u1 * a1;
        uint32_t lo = (uint16_t)f2bf(q0);
        uint32_t hi = (uint16_t)f2bf(q1);
        dst[c >> 1] = lo | (hi << 16);
      }
    }
    __syncthreads();

    // ---- prefetch next tile's x into the other buffer ----
    if (j < 2) {
      int tn2 = tn + 1;
      int wt2 = tn2 % 12, bh2 = tn2 / 12;
      int h2 = bh2 % 96, b2 = bh2 / 96, w02 = wt2 * 8;
      const float* xb = x + (size_t)b2 * 64 * 16 * 9216 + h2 * 96 + w02;
      float* xn = (j & 1) ? xsbuf0 : xsbuf1;
      for (int s = 0; s < 8; ++s) {
        int q = wv * 8 + s;
        int R = q * 32 + (l >> 1);
        gl_lds16(xb + (size_t)R * 9216 + (l & 1) * 4, xn + q * 256);
      }
    }

    // ---- main GEMM: out[16 o per wave][128 pos], K=192, bf16 MFMA ----
    f32x4 acc[8];
    #pragma unroll
    for (int nt = 0; nt < 8; ++nt) acc[nt] = (f32x4){bdv[0], bdv[1], bdv[2], bdv[3]};
    const char* bbase = smem + VALT_OFF + col * 400 + rg * 16;
    for (int ks = 0; ks < 6; ++ks) {
      short8 av = *(short8*)(smem + WDEF_OFF + ((wv * 6 + ks) * 64 + l) * 16);
      #pragma unroll
      for (int nt = 0; nt < 8; ++nt) {
        short8 bv = *(short8*)(bbase + nt * 6400 + ks * 64);
        acc[nt] = __builtin_amdgcn_mfma_f32_16x16x32_bf16(av, bv, acc[nt], 0, 0, 0);
      }
    }
    __syncthreads();   // all waves done reading val before it becomes staging

    // ---- epilogue: stage to LDS [o][132], then full-32B float4 stores ----
    #pragma unroll
    for (int nt = 0; nt < 8; ++nt) {
      int pos = nt * 16 + col;
      #pragma unroll
      for (int r = 0; r < 4; ++r) {
        int o = wv * 16 + rg * 4 + r;
        stg[o * 132 + pos] = acc[nt][r];
      }
    }
    __syncthreads();
    float* ob = out + (size_t)b * 64 * 16 * 9216 + h * 96 + w0;
    for (int s2 = t; s2 < 2048; s2 += 256) {
      int q = s2 >> 1, half = s2 & 1;
      int o = q >> 4, n = q & 15;
      float4 v = *(float4*)(stg + o * 132 + n * 8 + half * 4);
      *(float4*)(ob + (size_t)(o * 16 + n) * 9216 + half * 4) = v;
    }
    __syncthreads();
  }
}

extern "C" void kernel_launch(void* const* d_in, const int* in_sizes, int n_in,
                              void* d_out, int out_size, void* d_ws, size_t ws_size,
                              hipStream_t stream) {
  (void)in_sizes; (void)n_in; (void)d_ws; (void)ws_size; (void)out_size;
  static bool attr_set = false;
  if (!attr_set) {
    (void)hipFuncSetAttribute((const void*)deform_kernel,
                              hipFuncAttributeMaxDynamicSharedMemorySize, LDS_BYTES);
    attr_set = true;
  }
  const float* x     = (const float*)d_in[0];
  const float* w_off = (const float*)d_in[1];
  const float* b_off = (const float*)d_in[2];
  const float* w_def = (const float*)d_in[3];
  const float* b_def = (const float*)d_in[4];
  float* out = (float*)d_out;

  deform_kernel<<<dim3(768), dim3(256), LDS_BYTES, stream>>>(
      x, w_off, b_off, w_def, b_def, out);
}

// Round 4
// 205.387 us; speedup vs baseline: 3.0642x; 1.2134x over previous
//
#include <hip/hip_runtime.h>
#include <stdint.h>

// DeformableFusionAcrossFocus — round 4: occupancy-first restructure.
// x:(2,64,16,96,96) f32 | w_off:(6,64,3) | b_off:(6) | w_def:(64,64,3) | b_def:(64) -> out f32
// Tile = (b,h,8w): pos = n*8+w in [0,128). Grid 2304 blocks, 1 tile each, 3 blocks/CU.
// k-permutation kk -> (c = kk&63, k3 = kk>>6) shared by A-frag prep and B-frag builders.
// Waves split by pos: wave wv owns nt = 2wv..2wv+1 (32 pos), all 64 output channels.

typedef __attribute__((ext_vector_type(8))) short short8;
typedef __attribute__((ext_vector_type(4))) float f32x4;

// LDS (bytes):
//  [0,20480)      xs_t bf16 [pos][80 shorts] (row stride 160B, 64 c used, +16 pad)
//  [20480,36864)  xstage bf16 [c*128 + n*8 + w]  (dead after transpose)
//  [0,33792)      epilogue staging f32 [o][132]  (after GEMM; xs_t/xstage dead)
//  [36864,+1536)  A0 f32[384] | [+1536) A1 f32[384] | [+3072) R0B int[384] | [+4608) offs f32[6][128]
#define XT_OFF   0
#define XST_OFF  20480
#define PB       36864
#define A0_OFF   (PB)
#define A1_OFF   (PB + 1536)
#define R0_OFF   (PB + 3072)
#define OFFS_OFF (PB + 4608)
#define LDS_BYTES (PB + 7680)   // 44544 -> 3 blocks/CU

__device__ __forceinline__ short f2bf(float f) {
  union { float f; uint32_t u; } v; v.f = f;
  uint32_t r = (v.u + 0x7FFFu + ((v.u >> 16) & 1u)) >> 16;
  return (short)r;
}
__device__ __forceinline__ float bf2f(short s) {
  union { uint32_t u; float f; } v; v.u = ((uint32_t)(uint16_t)s) << 16; return v.f;
}

// ---- prep: pre-swizzle w_def (frags [0,1536)) and w_off (frags [1536,1920)) into ws ----
__global__ __launch_bounds__(256) void prep_kernel(
    const float* __restrict__ w_off, const float* __restrict__ w_def, short8* __restrict__ ws)
{
  int gid = blockIdx.x * 256 + threadIdx.x;
  if (gid < 1536) {                      // q = (mt*6+ks)*64 + lane
    int mt = gid / 384, ks = (gid % 384) >> 6, ll = gid & 63;
    int m = mt * 16 + (ll & 15), rgq = ll >> 4;
    short8 v;
    #pragma unroll
    for (int jj = 0; jj < 8; ++jj) {
      int kk = ks * 32 + rgq * 8 + jj;
      int c = kk & 63, k3 = kk >> 6;
      v[jj] = f2bf(w_def[m * 192 + c * 3 + k3]);
    }
    ws[gid] = v;
  } else if (gid < 1920) {               // q = ks*64 + lane (rows 6..15 zero)
    int q = gid - 1536;
    int ks = q >> 6, ll = q & 63;
    int m = ll & 15, rgq = ll >> 4;
    short8 v;
    #pragma unroll
    for (int jj = 0; jj < 8; ++jj) {
      int kk = ks * 32 + rgq * 8 + jj;
      int c = kk & 63, k3 = kk >> 6;
      v[jj] = (m < 6) ? f2bf(w_off[m * 192 + c * 3 + k3]) : (short)0;
    }
    ws[gid] = v;
  }
}

__global__ __launch_bounds__(256, 3) void deform_main(
    const float* __restrict__ x, const float* __restrict__ b_off,
    const float* __restrict__ b_def, const short8* __restrict__ wfr,
    float* __restrict__ out)
{
  extern __shared__ char smem[];
  const int t = threadIdx.x, wv = t >> 6, l = t & 63, col = l & 15, rg = l >> 4;
  const int tn = blockIdx.x;
  const int wt = tn % 12, bh = tn / 12;
  const int h = bh % 96, b = bh / 96, w0 = wt * 8;
  const float* xb = x + (size_t)b * 9437184 + h * 96 + w0;

  // ---- stage x -> bf16 [c][n][w] (coalesced: 2 lanes per 32B row) ----
  uint16_t* xst = (uint16_t*)(smem + XST_OFF);
  #pragma unroll
  for (int i = 0; i < 8; ++i) {
    int r = (t >> 1) + i * 128, half = t & 1;       // r = c*16+n
    float4 v = *(const float4*)(xb + (size_t)r * 9216 + half * 4);
    uint32_t p0 = (uint32_t)(uint16_t)f2bf(v.x) | ((uint32_t)(uint16_t)f2bf(v.y) << 16);
    uint32_t p1 = (uint32_t)(uint16_t)f2bf(v.z) | ((uint32_t)(uint16_t)f2bf(v.w) << 16);
    uint2 pk; pk.x = p0; pk.y = p1;
    *(uint2*)(xst + r * 8 + half * 4) = pk;
  }
  __syncthreads();

  // ---- transpose -> xs_t[pos][c] (b128 writes, 8 c per thread) ----
  #pragma unroll
  for (int i = 0; i < 4; ++i) {
    int item = t + 256 * i;                // 1024 = 128 pos x 8 cgroups
    int pos = item & 127, cg = item >> 7;
    short8 v;
    #pragma unroll
    for (int jj = 0; jj < 8; ++jj) v[jj] = (short)xst[(cg * 8 + jj) * 128 + pos];
    *(short8*)(smem + XT_OFF + pos * 160 + cg * 16) = v;
  }
  __syncthreads();

  // ---- offsets conv via MFMA: B-frag = one b128 (already bf16, already B-ordered) ----
  float* offs = (float*)(smem + OFFS_OFF);
  {
    f32x4 cacc[2] = {{0.f,0.f,0.f,0.f},{0.f,0.f,0.f,0.f}};
    const short8 zero = {0,0,0,0,0,0,0,0};
    for (int ks = 0; ks < 6; ++ks) {
      short8 av = wfr[1536 + ks * 64 + l];
      int k3 = ks >> 1;
      #pragma unroll
      for (int nt2 = 0; nt2 < 2; ++nt2) {
        int pos = (wv * 2 + nt2) * 16 + col;
        int n = pos >> 3, w = pos & 7;
        int row = n + k3 - 1;
        bool valid = (row >= 0) && (row < 16);
        int rcl = min(max(row, 0), 15);
        short8 bv = *(short8*)(smem + XT_OFF + (rcl * 8 + w) * 160 + rg * 16 + (ks & 1) * 64);
        bv = valid ? bv : zero;
        cacc[nt2] = __builtin_amdgcn_mfma_f32_16x16x32_bf16(av, bv, cacc[nt2], 0, 0, 0);
      }
    }
    #pragma unroll
    for (int nt2 = 0; nt2 < 2; ++nt2) {
      int pos = (wv * 2 + nt2) * 16 + col;
      #pragma unroll
      for (int r = 0; r < 4; ++r) {
        int rowo = rg * 4 + r;
        if (rowo < 6) offs[rowo * 128 + pos] = cacc[nt2][r];
      }
    }
  }
  __syncthreads();

  // ---- interp params per (k,pos): clipped tap weights + tap-row byte offset ----
  float* A0 = (float*)(smem + A0_OFF);
  float* A1 = (float*)(smem + A1_OFF);
  int*   R0 = (int*)(smem + R0_OFF);
  for (int it = t; it < 384; it += 256) {
    int k = it >> 7, pos = it & 127;
    int n = pos >> 3, w = pos & 7;
    float oy = offs[(2 * k) * 128 + pos] + b_off[2 * k];
    float ox = offs[(2 * k + 1) * 128 + pos] + b_off[2 * k + 1];
    float px = (float)(n - 1 + k) + ox;
    float x0f = floorf(px);
    float fx = px - x0f;
    int x0 = (int)x0f;
    float wy = fmaxf(0.f, 1.f - fabsf(oy));
    float wt1v = fx * wy;
    float wt0v = wy - wt1v;
    float a0, a1; int r0;
    if (x0 >= 0 && x0 < 15)  { r0 = x0; a0 = wt0v; a1 = wt1v; }
    else if (x0 == 15)       { r0 = 14; a0 = 0.f;  a1 = wt0v; }   // only row 15 (=x0)
    else if (x0 == -1)       { r0 = 0;  a0 = wt1v; a1 = 0.f;  }   // only row 0 (=x1)
    else                     { r0 = 0;  a0 = 0.f;  a1 = 0.f;  }
    A0[it] = a0; A1[it] = a1;
    R0[it] = (r0 * 8 + w) * 160;          // byte offset of tap row in xs_t
  }
  __syncthreads();

  // ---- main GEMM: 64 o x 32 pos per wave, K=192; B-frags built from taps on the fly ----
  f32x4 acc[4][2];
  #pragma unroll
  for (int mt = 0; mt < 4; ++mt) {
    float4 bd = *(const float4*)(b_def + mt * 16 + rg * 4);
    #pragma unroll
    for (int nt2 = 0; nt2 < 2; ++nt2) {
      acc[mt][nt2][0] = bd.x; acc[mt][nt2][1] = bd.y;
      acc[mt][nt2][2] = bd.z; acc[mt][nt2][3] = bd.w;
    }
  }
  #pragma unroll 1
  for (int k3 = 0; k3 < 3; ++k3) {
    float a0v[2], a1v[2]; int rb[2];
    #pragma unroll
    for (int nt2 = 0; nt2 < 2; ++nt2) {
      int idx = k3 * 128 + (wv * 2 + nt2) * 16 + col;
      a0v[nt2] = A0[idx]; a1v[nt2] = A1[idx]; rb[nt2] = R0[idx];
    }
    #pragma unroll
    for (int ks2 = 0; ks2 < 2; ++ks2) {
      int ks = k3 * 2 + ks2;
      short8 A[4];
      #pragma unroll
      for (int mt = 0; mt < 4; ++mt) A[mt] = wfr[(mt * 6 + ks) * 64 + l];
      #pragma unroll
      for (int nt2 = 0; nt2 < 2; ++nt2) {
        const char* base = smem + XT_OFF + rb[nt2] + rg * 16 + ks2 * 64;
        short8 x0 = *(const short8*)base;
        short8 x1 = *(const short8*)(base + 1280);   // tap row r0+1
        short8 bv;
        #pragma unroll
        for (int jj = 0; jj < 8; ++jj)
          bv[jj] = f2bf(a0v[nt2] * bf2f(x0[jj]) + a1v[nt2] * bf2f(x1[jj]));
        #pragma unroll
        for (int mt = 0; mt < 4; ++mt)
          acc[mt][nt2] = __builtin_amdgcn_mfma_f32_16x16x32_bf16(A[mt], bv, acc[mt][nt2], 0, 0, 0);
      }
    }
  }
  __syncthreads();   // xs_t dead; reuse as epilogue staging

  // ---- epilogue: stage [o][132] f32, then full-32B float4 stores ----
  float* stg = (float*)(smem + XT_OFF);
  #pragma unroll
  for (int mt = 0; mt < 4; ++mt) {
    #pragma unroll
    for (int nt2 = 0; nt2 < 2; ++nt2) {
      int pos = (wv * 2 + nt2) * 16 + col;
      #pragma unroll
      for (int r = 0; r < 4; ++r) {
        int o = mt * 16 + rg * 4 + r;
        stg[o * 132 + pos] = acc[mt][nt2][r];
      }
    }
  }
  __syncthreads();
  float* ob = out + (size_t)b * 9437184 + h * 96 + w0;
  for (int s2 = t; s2 < 2048; s2 += 256) {
    int q = s2 >> 1, half = s2 & 1;
    int o = q >> 4, n = q & 15;
    float4 v = *(float4*)(stg + o * 132 + n * 8 + half * 4);
    *(float4*)(ob + (size_t)(o * 16 + n) * 9216 + half * 4) = v;
  }
}

extern "C" void kernel_launch(void* const* d_in, const int* in_sizes, int n_in,
                              void* d_out, int out_size, void* d_ws, size_t ws_size,
                              hipStream_t stream) {
  (void)in_sizes; (void)n_in; (void)ws_size; (void)out_size;
  const float* x     = (const float*)d_in[0];
  const float* w_off = (const float*)d_in[1];
  const float* b_off = (const float*)d_in[2];
  const float* w_def = (const float*)d_in[3];
  const float* b_def = (const float*)d_in[4];
  float* out = (float*)d_out;
  short8* wfr = (short8*)d_ws;   // 1920 * 16B = 30720 B of scratch

  prep_kernel<<<dim3(8), dim3(256), 0, stream>>>(w_off, w_def, wfr);
  deform_main<<<dim3(2304), dim3(256), LDS_BYTES, stream>>>(x, b_off, b_def, wfr, out);
}